// Round 2
// baseline (3260.460 us; speedup 1.0000x reference)
//
#include <hip/hip_runtime.h>
#include <hip/hip_bf16.h>
#include <math.h>

// Problem constants
#define BDIM 8192
#define DDIM 1024
#define FDIM 4096
#define SDIM 4
#define HDIM 4
#define HD   256   // head dim = D/H

typedef unsigned short ushort_t;
typedef __bf16 bf16x8 __attribute__((ext_vector_type(8)));
typedef float  f32x4  __attribute__((ext_vector_type(4)));
typedef unsigned short u16x8 __attribute__((ext_vector_type(8)));

__device__ __forceinline__ float bf2f(ushort_t u) {
    union { float f; unsigned int i; } c;
    c.i = ((unsigned int)u) << 16;
    return c.f;
}
__device__ __forceinline__ ushort_t f2bf(float f) {
    union { float f; unsigned int i; } c; c.f = f;
    unsigned int x = c.i;
    unsigned int r = x + 0x7FFFu + ((x >> 16) & 1u);  // round-to-nearest-even
    return (ushort_t)(r >> 16);
}

// ---------------- prep kernels ----------------

// out[n*dim + k] = in[k*dim + n]  (transpose + cast), dim x dim
__global__ void transpose_cast(const float* __restrict__ in, ushort_t* __restrict__ out, int dim) {
    int i = blockIdx.x * 256 + threadIdx.x;
    int n = i / dim, k = i - n * dim;
    out[i] = f2bf(in[k * dim + n]);
}

// w1t[s][f][d] = sum_r g1a[s,i1,o1,r] * g1b[s,r,i2,o2]; f=o1*64+o2, d=i1*32+i2
// g1a: [S,32,64,16], g1b: [S,16,32,64]
__global__ void tt_w1t(const float* __restrict__ g1a, const float* __restrict__ g1b,
                       ushort_t* __restrict__ w1t) {
    int i = blockIdx.x * 256 + threadIdx.x;     // [S][F][D] flat
    int d = i & 1023;
    int rest = i >> 10;
    int f = rest & 4095;
    int s = rest >> 12;
    int i1 = d >> 5, i2 = d & 31;
    int o1 = f >> 6, o2 = f & 63;
    const float* pa = g1a + (((s * 32 + i1) * 64 + o1) << 4);         // contiguous r
    const float* pb = g1b + (size_t)s * 32768 + i2 * 64 + o2;         // + r*2048
    float acc = 0.f;
#pragma unroll
    for (int r = 0; r < 16; ++r) acc += pa[r] * pb[r * 2048];
    w1t[i] = f2bf(acc);
}

// w2t[s][d][f] = sum_r g2a[s,o1,i1,r] * g2b[s,r,o2,i2]; f=o1*64+o2, d=i1*32+i2
// g2a: [S,64,32,16], g2b: [S,16,64,32]
__global__ void tt_w2t(const float* __restrict__ g2a, const float* __restrict__ g2b,
                       ushort_t* __restrict__ w2t) {
    int i = blockIdx.x * 256 + threadIdx.x;     // [S][D][F] flat
    int f = i & 4095;
    int rest = i >> 12;
    int d = rest & 1023;
    int s = rest >> 10;
    int i1 = d >> 5, i2 = d & 31;
    int o1 = f >> 6, o2 = f & 63;
    const float* pa = g2a + (((s * 64 + o1) * 32 + i1) << 4);         // contiguous r
    const float* pb = g2b + (size_t)s * 32768 + o2 * 32 + i2;         // + r*2048
    float acc = 0.f;
#pragma unroll
    for (int r = 0; r < 16; ++r) acc += pa[r] * pb[r * 2048];
    w2t[i] = f2bf(acc);
}

// ---------------- GEMM: C[M,N] = A[M,K] * Bt[N,K]^T ----------------
// bf16 (or fp32->bf16 inline when AF32) inputs, fp32 accumulate.
// 64x64 block tile, 4 waves (2x2), each wave 32x32 via 2x2 MFMA 16x16x32. BK=32.
// EPI: 0 = store bf16; 1 = exact gelu -> bf16; 2 = +bias -> bf16; 3 = +bias -> f32
template <int EPI, bool AF32>
__global__ __launch_bounds__(256) void gemm_bt(
    const void* __restrict__ Avoid,
    const ushort_t* __restrict__ Bt,
    void* __restrict__ Cout,
    const float* __restrict__ bias,
    int M, int N, int K)
{
    __shared__ __align__(16) ushort_t As[64][32];
    __shared__ __align__(16) ushort_t Bs[64][32];

    const int tid  = threadIdx.x;
    const int lane = tid & 63;
    const int wave = tid >> 6;
    const int wm   = (wave >> 1) * 32;
    const int wn   = (wave & 1) * 32;
    const int quad = lane >> 4;
    const int l16  = lane & 15;

    const int bm = blockIdx.x * 64;
    const int bn = blockIdx.y * 64;

    const int lrow = tid >> 2;         // 0..63
    const int lcol = (tid & 3) << 3;   // 0,8,16,24

    f32x4 acc00 = {0.f,0.f,0.f,0.f}, acc01 = {0.f,0.f,0.f,0.f};
    f32x4 acc10 = {0.f,0.f,0.f,0.f}, acc11 = {0.f,0.f,0.f,0.f};

    for (int k0 = 0; k0 < K; k0 += 32) {
        if (AF32) {
            const float* Af = (const float*)Avoid;
            const float* ap = Af + (size_t)(bm + lrow) * K + k0 + lcol;
            float4 f0 = *(const float4*)ap;
            float4 f1 = *(const float4*)(ap + 4);
            u16x8 t;
            t[0] = f2bf(f0.x); t[1] = f2bf(f0.y); t[2] = f2bf(f0.z); t[3] = f2bf(f0.w);
            t[4] = f2bf(f1.x); t[5] = f2bf(f1.y); t[6] = f2bf(f1.z); t[7] = f2bf(f1.w);
            *(u16x8*)&As[lrow][lcol] = t;
        } else {
            const ushort_t* Ab = (const ushort_t*)Avoid;
            *(u16x8*)&As[lrow][lcol] = *(const u16x8*)(Ab + (size_t)(bm + lrow) * K + k0 + lcol);
        }
        *(u16x8*)&Bs[lrow][lcol] = *(const u16x8*)(Bt + (size_t)(bn + lrow) * K + k0 + lcol);
        __syncthreads();

        bf16x8 a0 = *(const bf16x8*)&As[wm + l16][quad * 8];
        bf16x8 a1 = *(const bf16x8*)&As[wm + 16 + l16][quad * 8];
        bf16x8 b0 = *(const bf16x8*)&Bs[wn + l16][quad * 8];
        bf16x8 b1 = *(const bf16x8*)&Bs[wn + 16 + l16][quad * 8];

        acc00 = __builtin_amdgcn_mfma_f32_16x16x32_bf16(a0, b0, acc00, 0, 0, 0);
        acc01 = __builtin_amdgcn_mfma_f32_16x16x32_bf16(a0, b1, acc01, 0, 0, 0);
        acc10 = __builtin_amdgcn_mfma_f32_16x16x32_bf16(a1, b0, acc10, 0, 0, 0);
        acc11 = __builtin_amdgcn_mfma_f32_16x16x32_bf16(a1, b1, acc11, 0, 0, 0);
        __syncthreads();
    }

    // Epilogue. C/D layout (m89-verified): col = lane&15, row = quad*4 + reg.
    f32x4 accs[2][2] = {{acc00, acc01}, {acc10, acc11}};
#pragma unroll
    for (int ms = 0; ms < 2; ++ms) {
#pragma unroll
        for (int ns = 0; ns < 2; ++ns) {
            int row0 = bm + wm + ms * 16 + quad * 4;
            int col  = bn + wn + ns * 16 + l16;
#pragma unroll
            for (int r = 0; r < 4; ++r) {
                float cv = accs[ms][ns][r];
                if (EPI == 1) cv = 0.5f * cv * (1.0f + erff(cv * 0.7071067811865476f));
                if (EPI == 2 || EPI == 3) cv += bias[col];
                size_t idx = (size_t)(row0 + r) * N + col;
                if (EPI == 3) ((float*)Cout)[idx] = cv;
                else          ((ushort_t*)Cout)[idx] = f2bf(cv);
            }
        }
    }
}

// ---------------- per-s score kernel ----------------
// sc_s[b*H + h] = (q[b,h,:] . k_s[b,h,:]) / sqrt(hd).  One block per b, wave = head.
__global__ __launch_bounds__(256) void score_kernel(
    const ushort_t* __restrict__ q, const ushort_t* __restrict__ ks,
    float* __restrict__ sc_s)
{
    int b    = blockIdx.x;
    int head = threadIdx.x >> 6;
    int lane = threadIdx.x & 63;
    size_t off = (size_t)b * DDIM + head * HD + lane * 4;
    float p = 0.f;
#pragma unroll
    for (int j = 0; j < 4; ++j) p += bf2f(q[off + j]) * bf2f(ks[off + j]);
#pragma unroll
    for (int m = 1; m < 64; m <<= 1) p += __shfl_xor(p, m, 64);
    if (lane == 0) sc_s[b * HDIM + head] = p * 0.0625f;   // 1/sqrt(256)
}

// ---------------- attention collapse over S ----------------
// scores:[S][B][H] f32, v:[S][B][D] bf16 -> o:[B][D] bf16. Block per b, wave = head.
__global__ __launch_bounds__(256) void attn_collapse(
    const float* __restrict__ scores, const ushort_t* __restrict__ v,
    ushort_t* __restrict__ o)
{
    int b    = blockIdx.x;
    int head = threadIdx.x >> 6;
    int lane = threadIdx.x & 63;
    int off  = head * HD + lane * 4;

    float sc[4];
#pragma unroll
    for (int s = 0; s < 4; ++s) sc[s] = scores[(size_t)s * BDIM * HDIM + b * HDIM + head];
    float mx = fmaxf(fmaxf(sc[0], sc[1]), fmaxf(sc[2], sc[3]));
    float e[4], den = 0.f;
#pragma unroll
    for (int s = 0; s < 4; ++s) { e[s] = expf(sc[s] - mx); den += e[s]; }
    float inv = 1.0f / den;

    float ov[4] = {0.f, 0.f, 0.f, 0.f};
#pragma unroll
    for (int s = 0; s < 4; ++s) {
        float w = e[s] * inv;
        size_t vidx = ((size_t)s * BDIM + b) * DDIM + off;
#pragma unroll
        for (int j = 0; j < 4; ++j) ov[j] += w * bf2f(v[vidx + j]);
    }
    size_t oidx = (size_t)b * DDIM + off;
#pragma unroll
    for (int j = 0; j < 4; ++j) o[oidx + j] = f2bf(ov[j]);
}

// ---------------- launch ----------------

extern "C" void kernel_launch(void* const* d_in, const int* in_sizes, int n_in,
                              void* d_out, int out_size, void* d_ws, size_t ws_size,
                              hipStream_t stream)
{
    (void)in_sizes; (void)n_in; (void)out_size; (void)ws_size;

    const float* x   = (const float*)d_in[0];
    const float* g1a = (const float*)d_in[1];
    const float* g1b = (const float*)d_in[2];
    const float* g2a = (const float*)d_in[3];
    const float* g2b = (const float*)d_in[4];
    const float* wq  = (const float*)d_in[5];
    const float* bq  = (const float*)d_in[6];
    const float* wk  = (const float*)d_in[7];
    const float* bk  = (const float*)d_in[8];
    const float* wv  = (const float*)d_in[9];
    const float* bv  = (const float*)d_in[10];
    const float* wo  = (const float*)d_in[11];
    const float* bo  = (const float*)d_in[12];

    // Workspace layout (~244 MB total, elements of ushort unless noted):
    ushort_t* ws = (ushort_t*)d_ws;
    size_t off = 0;
    ushort_t* w1t = ws + off; off += (size_t)SDIM * FDIM * DDIM;   // [S][F][D]  33.6 MB
    ushort_t* w2t = ws + off; off += (size_t)SDIM * DDIM * FDIM;   // [S][D][F]  33.6 MB
    ushort_t* wqt = ws + off; off += (size_t)DDIM * DDIM;          //             2.1 MB
    ushort_t* wkt = ws + off; off += (size_t)DDIM * DDIM;
    ushort_t* wvt = ws + off; off += (size_t)DDIM * DDIM;
    ushort_t* wot = ws + off; off += (size_t)DDIM * DDIM;
    ushort_t* qb  = ws + off; off += (size_t)BDIM * DDIM;          //            16.8 MB
    ushort_t* hs  = ws + off; off += (size_t)BDIM * FDIM;          // h_s slab   67.1 MB (aliases k_s, ob)
    ushort_t* ys  = ws + off; off += (size_t)BDIM * DDIM;          //            16.8 MB
    ushort_t* vb  = ws + off; off += (size_t)SDIM * BDIM * DDIM;   //            67.1 MB
    float*  scores = (float*)(ws + off);                           // [S][B][H]   0.5 MB
    ushort_t* ks  = hs;                                            // alias (h_s dead when used)
    ushort_t* ob  = hs;                                            // alias (after s-loop)

    // prep: transposes + TT contractions (all tiny)
    transpose_cast<<<(DDIM * DDIM) / 256, 256, 0, stream>>>(wq, wqt, DDIM);
    transpose_cast<<<(DDIM * DDIM) / 256, 256, 0, stream>>>(wk, wkt, DDIM);
    transpose_cast<<<(DDIM * DDIM) / 256, 256, 0, stream>>>(wv, wvt, DDIM);
    transpose_cast<<<(DDIM * DDIM) / 256, 256, 0, stream>>>(wo, wot, DDIM);
    tt_w1t<<<(SDIM * FDIM * DDIM) / 256, 256, 0, stream>>>(g1a, g1b, w1t);
    tt_w2t<<<(SDIM * DDIM * FDIM) / 256, 256, 0, stream>>>(g2a, g2b, w2t);

    // q = x @ wq + bq  (fp32 A inline-cast)
    {
        dim3 g(BDIM / 64, DDIM / 64, 1);
        gemm_bt<2, true><<<g, 256, 0, stream>>>(x, wqt, qb, bq, BDIM, DDIM, DDIM);
    }

    // per-superposition-branch pipeline (reuses hs/ys/ks)
    for (int s = 0; s < SDIM; ++s) {
        // h_s = gelu(x @ w1[s])   M=B, N=F, K=D
        {
            dim3 g(BDIM / 64, FDIM / 64, 1);
            gemm_bt<1, true><<<g, 256, 0, stream>>>(
                x, w1t + (size_t)s * FDIM * DDIM, hs, nullptr, BDIM, FDIM, DDIM);
        }
        // y_s = h_s @ w2[s]       M=B, N=D, K=F
        {
            dim3 g(BDIM / 64, DDIM / 64, 1);
            gemm_bt<0, false><<<g, 256, 0, stream>>>(
                hs, w2t + (size_t)s * DDIM * FDIM, ys, nullptr, BDIM, DDIM, FDIM);
        }
        // k_s = y_s @ wk + bk   (k_s aliases hs; h_s dead here)
        {
            dim3 g(BDIM / 64, DDIM / 64, 1);
            gemm_bt<2, false><<<g, 256, 0, stream>>>(ys, wkt, ks, bk, BDIM, DDIM, DDIM);
        }
        // v_s = y_s @ wv + bv  -> vb[s]
        {
            dim3 g(BDIM / 64, DDIM / 64, 1);
            gemm_bt<2, false><<<g, 256, 0, stream>>>(
                ys, wvt, vb + (size_t)s * BDIM * DDIM, bv, BDIM, DDIM, DDIM);
        }
        // scores[s] = (q . k_s) / sqrt(hd)
        score_kernel<<<BDIM, 256, 0, stream>>>(qb, ks, scores + (size_t)s * BDIM * HDIM);
    }

    // softmax over s + weighted V sum  (ob aliases hs)
    attn_collapse<<<BDIM, 256, 0, stream>>>(scores, vb, ob);

    // out = o @ wo + bo  (fp32 out)
    {
        dim3 g(BDIM / 64, DDIM / 64, 1);
        gemm_bt<3, false><<<g, 256, 0, stream>>>(ob, wot, d_out, bo, BDIM, DDIM, DDIM);
    }
}

// Round 3
// 1330.053 us; speedup vs baseline: 2.4514x; 2.4514x over previous
//
#include <hip/hip_runtime.h>
#include <hip/hip_bf16.h>
#include <math.h>

// Problem constants
#define BDIM 8192
#define DDIM 1024
#define FDIM 4096
#define SDIM 4
#define HDIM 4
#define HD   256   // head dim = D/H

typedef unsigned short ushort_t;
typedef __bf16 bf16x8 __attribute__((ext_vector_type(8)));
typedef float  f32x4  __attribute__((ext_vector_type(4)));
typedef unsigned short u16x8 __attribute__((ext_vector_type(8)));
typedef unsigned short u16x4 __attribute__((ext_vector_type(4)));

__device__ __forceinline__ float bf2f(ushort_t u) {
    union { float f; unsigned int i; } c;
    c.i = ((unsigned int)u) << 16;
    return c.f;
}
__device__ __forceinline__ ushort_t f2bf(float f) {
    union { float f; unsigned int i; } c; c.f = f;
    unsigned int x = c.i;
    unsigned int r = x + 0x7FFFu + ((x >> 16) & 1u);  // round-to-nearest-even
    return (ushort_t)(r >> 16);
}

__device__ __forceinline__ void async_copy16(const ushort_t* g, ushort_t* l) {
    __builtin_amdgcn_global_load_lds(
        (const __attribute__((address_space(1))) void*)g,
        (__attribute__((address_space(3))) void*)l, 16, 0, 0);
}

// ---------------- prep kernels ----------------

// x (fp32, [B][D]) -> bf16, 8 elems/thread
__global__ __launch_bounds__(256) void cast_x(const float* __restrict__ in, ushort_t* __restrict__ out) {
    int i = (blockIdx.x * 256 + threadIdx.x) * 8;
    float4 f0 = *(const float4*)(in + i);
    float4 f1 = *(const float4*)(in + i + 4);
    u16x8 t;
    t[0] = f2bf(f0.x); t[1] = f2bf(f0.y); t[2] = f2bf(f0.z); t[3] = f2bf(f0.w);
    t[4] = f2bf(f1.x); t[5] = f2bf(f1.y); t[6] = f2bf(f1.z); t[7] = f2bf(f1.w);
    *(u16x8*)(out + i) = t;
}

// out[n][k] = in[k][n], 1024x1024, LDS 64x64 tile, coalesced both sides.
__global__ __launch_bounds__(256) void transpose_cast_tiled(const float* __restrict__ in,
                                                            ushort_t* __restrict__ out) {
    __shared__ float t[64][65];
    int bx = blockIdx.x * 64;   // out-row block = in-col block
    int by = blockIdx.y * 64;   // out-col block = in-row block
    int tr = threadIdx.x >> 4;          // 0..15
    int tc = (threadIdx.x & 15) * 4;    // 0..60
#pragma unroll
    for (int i = 0; i < 4; ++i) {
        int row = tr + i * 16;
        float4 v = *(const float4*)&in[(size_t)(by + row) * DDIM + bx + tc];
        t[row][tc] = v.x; t[row][tc + 1] = v.y; t[row][tc + 2] = v.z; t[row][tc + 3] = v.w;
    }
    __syncthreads();
#pragma unroll
    for (int i = 0; i < 4; ++i) {
        int row = tr + i * 16;
        u16x4 o4;
#pragma unroll
        for (int j = 0; j < 4; ++j) o4[j] = f2bf(t[tc + j][row]);
        *(u16x4*)&out[(size_t)(bx + row) * DDIM + by + tc] = o4;
    }
}

// ---------------- TT contractions (per superposition branch s) ----------------
// w1s[f][d] = sum_r g1a_s[i1,o1,r] * g1b_s[r,i2,o2]; f=o1*64+o2, d=i1*32+i2
// g1a_s: [32][64][16], g1b_s: [16][32][64]. Grid 256 blocks; block = 16 f-rows (fixed o1).
__global__ __launch_bounds__(256) void tt_w1s(const float* __restrict__ g1a_s,
                                              const float* __restrict__ g1b_s,
                                              ushort_t* __restrict__ w1s) {
    __shared__ float a_lds[512];    // [i1][r]
    __shared__ float b_lds[8192];   // [r][o2'][i2]
    int b  = blockIdx.x;            // 0..255
    int o1 = b >> 2;
    int o2_0 = (b & 3) * 16;
    int tid = threadIdx.x;
    for (int idx = tid; idx < 512; idx += 256) {
        int i1 = idx >> 4, r = idx & 15;
        a_lds[idx] = g1a_s[i1 * 1024 + o1 * 16 + r];
    }
    for (int idx = tid; idx < 8192; idx += 256) {
        int i2 = idx & 31, o2p = (idx >> 5) & 15, r = idx >> 9;
        b_lds[idx] = g1b_s[r * 2048 + i2 * 64 + o2_0 + o2p];   // b_lds[(r*16+o2p)*32+i2]
    }
    __syncthreads();
    int wave = tid >> 6, lane = tid & 63;
    for (int d0 = 0; d0 < 1024; d0 += 64) {
        int d = d0 + lane;
        int i1 = d >> 5, i2 = d & 31;
        float a[16];
#pragma unroll
        for (int r = 0; r < 16; ++r) a[r] = a_lds[i1 * 16 + r];
#pragma unroll
        for (int jj = 0; jj < 4; ++jj) {
            int fp = wave * 4 + jj;
            float acc = 0.f;
#pragma unroll
            for (int r = 0; r < 16; ++r) acc += a[r] * b_lds[(r * 16 + fp) * 32 + i2];
            w1s[(size_t)(b * 16 + fp) * DDIM + d] = f2bf(acc);
        }
    }
}

// w2s[d][f] = sum_r g2a_s[o1,i1,r] * g2b_s[r,o2,i2]; f=o1*64+o2, d=i1*32+i2
// g2a_s: [64][32][16], g2b_s: [16][64][32]. Grid 128 blocks; block = 8 d-rows (fixed i1).
__global__ __launch_bounds__(256) void tt_w2s(const float* __restrict__ g2a_s,
                                              const float* __restrict__ g2b_s,
                                              ushort_t* __restrict__ w2s) {
    __shared__ float a_lds[1024];   // [o1][r]
    __shared__ float b_lds[8192];   // [r][i2'][o2]
    int b  = blockIdx.x;            // 0..127
    int i1 = b >> 2;
    int i2_0 = (b & 3) * 8;
    int tid = threadIdx.x;
    for (int idx = tid; idx < 1024; idx += 256) {
        int o1 = idx >> 4, r = idx & 15;
        a_lds[idx] = g2a_s[o1 * 512 + i1 * 16 + r];
    }
    for (int idx = tid; idx < 8192; idx += 256) {
        int o2 = idx & 63, i2p = (idx >> 6) & 7, r = idx >> 9;
        b_lds[idx] = g2b_s[r * 2048 + o2 * 32 + i2_0 + i2p];   // b_lds[(r*8+i2p)*64+o2]
    }
    __syncthreads();
    int wave = tid >> 6, lane = tid & 63;
    for (int f0 = 0; f0 < 4096; f0 += 64) {
        int o1 = f0 >> 6;
        float a[16];
#pragma unroll
        for (int r = 0; r < 16; ++r) a[r] = a_lds[o1 * 16 + r];
#pragma unroll
        for (int jj = 0; jj < 2; ++jj) {
            int dp = wave * 2 + jj;     // 0..7; i2' == dp
            float acc = 0.f;
#pragma unroll
            for (int r = 0; r < 16; ++r) acc += a[r] * b_lds[(r * 8 + dp) * 64 + lane];
            w2s[(size_t)(b * 8 + dp) * FDIM + f0 + lane] = f2bf(acc);
        }
    }
}

// ---------------- GEMM: C[M,N] = A[M,K] * Bt[N,K]^T ----------------
// m97-ladder structure: 128x128 tile, 4 waves (2x2), each wave 64x64 via 4x4
// MFMA 16x16x32 tiles. BK=32. global_load_lds width-16 staging (wave-uniform
// LDS base + lane*16B; As/Bs unpadded [128][32] so lane order == LDS order).
// EPI: 0 = store bf16; 1 = exact gelu -> bf16; 2 = +bias -> bf16; 3 = +bias -> f32
template <int EPI>
__global__ __launch_bounds__(256) void gemm128(
    const ushort_t* __restrict__ A,
    const ushort_t* __restrict__ Bt,
    void* __restrict__ Cout,
    const float* __restrict__ bias,
    int M, int N, int K)
{
    __shared__ __align__(16) ushort_t As[128 * 32];
    __shared__ __align__(16) ushort_t Bs[128 * 32];

    const int tid  = threadIdx.x;
    const int lane = tid & 63;
    const int wave = tid >> 6;
    const int wm   = (wave >> 1) * 64;
    const int wn   = (wave & 1) * 64;
    const int quad = lane >> 4;
    const int l16  = lane & 15;
    const int bm = blockIdx.x * 128;
    const int bn = blockIdx.y * 128;

    // staging: issue t (= wave*2+i) covers rows [t*16, t*16+16); lane -> row t*16+lane/4,
    // 16B-chunk lane%4. LDS dest = base + t*1024B (+ implicit lane*16B).
    const int srow = lane >> 2;
    const int scol = (lane & 3) * 8;
    const ushort_t* ga0 = A  + (size_t)(bm + wave * 32 + srow) * K + scol;
    const ushort_t* ga1 = A  + (size_t)(bm + wave * 32 + 16 + srow) * K + scol;
    const ushort_t* gb0 = Bt + (size_t)(bn + wave * 32 + srow) * K + scol;
    const ushort_t* gb1 = Bt + (size_t)(bn + wave * 32 + 16 + srow) * K + scol;
    ushort_t* la0 = As + wave * 1024;
    ushort_t* la1 = As + wave * 1024 + 512;
    ushort_t* lb0 = Bs + wave * 1024;
    ushort_t* lb1 = Bs + wave * 1024 + 512;

    f32x4 acc[4][4] = {};

    for (int k0 = 0; k0 < K; k0 += 32) {
        __syncthreads();                    // all waves done reading previous tile
        async_copy16(ga0 + k0, la0);
        async_copy16(ga1 + k0, la1);
        async_copy16(gb0 + k0, lb0);
        async_copy16(gb1 + k0, lb1);
        __syncthreads();                    // drains vmcnt(0): staged tile visible

        bf16x8 af[4], bfb[4];
#pragma unroll
        for (int t = 0; t < 4; ++t) {
            af[t]  = *(const bf16x8*)&As[(wm + t * 16 + l16) * 32 + quad * 8];
            bfb[t] = *(const bf16x8*)&Bs[(wn + t * 16 + l16) * 32 + quad * 8];
        }
#pragma unroll
        for (int mt = 0; mt < 4; ++mt)
#pragma unroll
            for (int nt = 0; nt < 4; ++nt)
                acc[mt][nt] = __builtin_amdgcn_mfma_f32_16x16x32_bf16(af[mt], bfb[nt], acc[mt][nt], 0, 0, 0);
    }

    // Epilogue. C/D layout (m89-verified): col = lane&15, row = quad*4 + reg.
#pragma unroll
    for (int mt = 0; mt < 4; ++mt) {
        int row0 = bm + wm + mt * 16 + quad * 4;
#pragma unroll
        for (int nt = 0; nt < 4; ++nt) {
            int col = bn + wn + nt * 16 + l16;
#pragma unroll
            for (int r = 0; r < 4; ++r) {
                float cv = acc[mt][nt][r];
                if (EPI == 1) cv = 0.5f * cv * (1.0f + erff(cv * 0.7071067811865476f));
                if (EPI == 2 || EPI == 3) cv += bias[col];
                size_t idx = (size_t)(row0 + r) * N + col;
                if (EPI == 3) ((float*)Cout)[idx] = cv;
                else          ((ushort_t*)Cout)[idx] = f2bf(cv);
            }
        }
    }
}

// ---------------- per-s score kernel ----------------
__global__ __launch_bounds__(256) void score_kernel(
    const ushort_t* __restrict__ q, const ushort_t* __restrict__ ks,
    float* __restrict__ sc_s)
{
    int b    = blockIdx.x;
    int head = threadIdx.x >> 6;
    int lane = threadIdx.x & 63;
    size_t off = (size_t)b * DDIM + head * HD + lane * 4;
    float p = 0.f;
#pragma unroll
    for (int j = 0; j < 4; ++j) p += bf2f(q[off + j]) * bf2f(ks[off + j]);
#pragma unroll
    for (int m = 1; m < 64; m <<= 1) p += __shfl_xor(p, m, 64);
    if (lane == 0) sc_s[b * HDIM + head] = p * 0.0625f;   // 1/sqrt(256)
}

// ---------------- attention collapse over S ----------------
__global__ __launch_bounds__(256) void attn_collapse(
    const float* __restrict__ scores, const ushort_t* __restrict__ v,
    ushort_t* __restrict__ o)
{
    int b    = blockIdx.x;
    int head = threadIdx.x >> 6;
    int lane = threadIdx.x & 63;
    int off  = head * HD + lane * 4;

    float sc[4];
#pragma unroll
    for (int s = 0; s < 4; ++s) sc[s] = scores[(size_t)s * BDIM * HDIM + b * HDIM + head];
    float mx = fmaxf(fmaxf(sc[0], sc[1]), fmaxf(sc[2], sc[3]));
    float e[4], den = 0.f;
#pragma unroll
    for (int s = 0; s < 4; ++s) { e[s] = expf(sc[s] - mx); den += e[s]; }
    float inv = 1.0f / den;

    float ov[4] = {0.f, 0.f, 0.f, 0.f};
#pragma unroll
    for (int s = 0; s < 4; ++s) {
        float w = e[s] * inv;
        size_t vidx = ((size_t)s * BDIM + b) * DDIM + off;
#pragma unroll
        for (int j = 0; j < 4; ++j) ov[j] += w * bf2f(v[vidx + j]);
    }
    size_t oidx = (size_t)b * DDIM + off;
#pragma unroll
    for (int j = 0; j < 4; ++j) o[oidx + j] = f2bf(ov[j]);
}

// ---------------- launch ----------------

extern "C" void kernel_launch(void* const* d_in, const int* in_sizes, int n_in,
                              void* d_out, int out_size, void* d_ws, size_t ws_size,
                              hipStream_t stream)
{
    (void)in_sizes; (void)n_in; (void)out_size; (void)ws_size;

    const float* x   = (const float*)d_in[0];
    const float* g1a = (const float*)d_in[1];
    const float* g1b = (const float*)d_in[2];
    const float* g2a = (const float*)d_in[3];
    const float* g2b = (const float*)d_in[4];
    const float* wq  = (const float*)d_in[5];
    const float* bq  = (const float*)d_in[6];
    const float* wk  = (const float*)d_in[7];
    const float* bk  = (const float*)d_in[8];
    const float* wv  = (const float*)d_in[9];
    const float* bv  = (const float*)d_in[10];
    const float* wo  = (const float*)d_in[11];
    const float* bo  = (const float*)d_in[12];

    // Workspace layout (~210 MB, ushort elements; per-s TT buffers -> fits well
    // under the 244 MB known-good footprint):
    ushort_t* ws = (ushort_t*)d_ws;
    size_t off = 0;
    ushort_t* wqt = ws + off; off += (size_t)DDIM * DDIM;          //  2.1 MB
    ushort_t* wkt = ws + off; off += (size_t)DDIM * DDIM;
    ushort_t* wvt = ws + off; off += (size_t)DDIM * DDIM;
    ushort_t* wot = ws + off; off += (size_t)DDIM * DDIM;
    ushort_t* xbf = ws + off; off += (size_t)BDIM * DDIM;          // 16.8 MB
    ushort_t* qb  = ws + off; off += (size_t)BDIM * DDIM;          // 16.8 MB
    ushort_t* w1s = ws + off; off += (size_t)FDIM * DDIM;          //  8.4 MB  [F][D]
    ushort_t* w2s = ws + off; off += (size_t)DDIM * FDIM;          //  8.4 MB  [D][F]
    ushort_t* hs  = ws + off; off += (size_t)BDIM * FDIM;          // 67.1 MB (aliases ks, ob)
    ushort_t* ys  = ws + off; off += (size_t)BDIM * DDIM;          // 16.8 MB
    ushort_t* vb  = ws + off; off += (size_t)SDIM * BDIM * DDIM;   // 67.1 MB
    float*  scores = (float*)(ws + off);                           //  0.5 MB [S][B][H]
    ushort_t* ks  = hs;   // alias: h_s dead once y_s computed
    ushort_t* ob  = hs;   // alias: after s-loop

    // prep
    cast_x<<<(BDIM * DDIM) / (256 * 8), 256, 0, stream>>>(x, xbf);
    {
        dim3 g(DDIM / 64, DDIM / 64);
        transpose_cast_tiled<<<g, 256, 0, stream>>>(wq, wqt);
        transpose_cast_tiled<<<g, 256, 0, stream>>>(wk, wkt);
        transpose_cast_tiled<<<g, 256, 0, stream>>>(wv, wvt);
        transpose_cast_tiled<<<g, 256, 0, stream>>>(wo, wot);
    }

    // q = x @ wq + bq
    {
        dim3 g(BDIM / 128, DDIM / 128);
        gemm128<2><<<g, 256, 0, stream>>>(xbf, wqt, qb, bq, BDIM, DDIM, DDIM);
    }

    // per-superposition-branch pipeline
    for (int s = 0; s < SDIM; ++s) {
        const float* g1a_s = g1a + (size_t)s * 32768;
        const float* g1b_s = g1b + (size_t)s * 32768;
        const float* g2a_s = g2a + (size_t)s * 32768;
        const float* g2b_s = g2b + (size_t)s * 32768;

        tt_w1s<<<256, 256, 0, stream>>>(g1a_s, g1b_s, w1s);
        {   // h_s = gelu(x @ w1[s])   M=B, N=F, K=D
            dim3 g(BDIM / 128, FDIM / 128);
            gemm128<1><<<g, 256, 0, stream>>>(xbf, w1s, hs, nullptr, BDIM, FDIM, DDIM);
        }
        tt_w2s<<<128, 256, 0, stream>>>(g2a_s, g2b_s, w2s);
        {   // y_s = h_s @ w2[s]       M=B, N=D, K=F
            dim3 g(BDIM / 128, DDIM / 128);
            gemm128<0><<<g, 256, 0, stream>>>(hs, w2s, ys, nullptr, BDIM, DDIM, FDIM);
        }
        {   // k_s = y_s @ wk + bk  (ks aliases hs; hs dead after GEMM2)
            dim3 g(BDIM / 128, DDIM / 128);
            gemm128<2><<<g, 256, 0, stream>>>(ys, wkt, ks, bk, BDIM, DDIM, DDIM);
            // v_s = y_s @ wv + bv
            gemm128<2><<<g, 256, 0, stream>>>(ys, wvt, vb + (size_t)s * BDIM * DDIM, bv,
                                              BDIM, DDIM, DDIM);
        }
        score_kernel<<<BDIM, 256, 0, stream>>>(qb, ks, scores + (size_t)s * BDIM * HDIM);
    }

    // softmax over s + weighted V sum  (ob aliases hs)
    attn_collapse<<<BDIM, 256, 0, stream>>>(scores, vb, ob);

    // out = o @ wo + bo  (fp32 out)
    {
        dim3 g(BDIM / 128, DDIM / 128);
        gemm128<3><<<g, 256, 0, stream>>>(ob, wot, d_out, bo, BDIM, DDIM, DDIM);
    }
}